// Round 16
// baseline (436.241 us; speedup 1.0000x reference)
//
#include <hip/hip_runtime.h>
#include <cstdint>

#define NTOK 2048
#define DMODEL 1024
#define NHEADS 16
#define HD 64
#define BATCH 2
#define EPSF 1e-10f
#define LOG2E 1.44269504088896340736f
#define LN2   0.69314718055994530942f

typedef __attribute__((ext_vector_type(8))) short bf16x8;
typedef __attribute__((ext_vector_type(8))) _Float16 f16x8;
typedef __attribute__((ext_vector_type(4))) float f32x4;

__device__ __forceinline__ float bf2f(unsigned short u){
  union { unsigned int i; float f; } c; c.i = ((unsigned int)u) << 16; return c.f;
}
__device__ __forceinline__ unsigned short f2bf(float f){
  union { float f; unsigned int u; } c; c.f = f;
  unsigned int u = c.u;
  unsigned int r = (u + 0x7FFFu + ((u >> 16) & 1u)) >> 16;
  return (unsigned short)r;
}
__device__ __forceinline__ unsigned short f2h(float f){
  union { _Float16 h; unsigned short u; } c; c.h = (_Float16)f; return c.u;
}
__device__ __forceinline__ float h2f(unsigned short u){
  union { unsigned short u; _Float16 h; } c; c.u = u; return (float)c.h;
}

// bare v_exp_f32 / v_log_f32 (2^x, log2 x) -- avoids __expf's implicit
// *log2e v_mul. All softmax inputs are pre-scaled into log2 domain.
__device__ __forceinline__ float fexp2(float x){
#if __has_builtin(__builtin_amdgcn_exp2f)
  return __builtin_amdgcn_exp2f(x);
#else
  return exp2f(x);
#endif
}
__device__ __forceinline__ float flog2(float x){
#if __has_builtin(__builtin_amdgcn_logf)
  return __builtin_amdgcn_logf(x);
#else
  return __log2f(x);
#endif
}

__device__ __forceinline__ void async16(const unsigned short* g, unsigned short* lds_base){
  __builtin_amdgcn_global_load_lds((const __attribute__((address_space(1))) unsigned int*)g,
                                   (__attribute__((address_space(3))) unsigned int*)lds_base,
                                   16, 0, 0);
}

// DPP 16-lane reductions (VALU pipe; replaces ds-pipe __shfl_xor chains).
template<int CTRL>
__device__ __forceinline__ float dppmov(float x){
  union { float f; int i; } a, r;
  a.f = x;
  r.i = __builtin_amdgcn_update_dpp(0, a.i, CTRL, 0xF, 0xF, true);
  return r.f;
}
__device__ __forceinline__ float red16_max(float x){
  x = fmaxf(x, dppmov<0xB1>(x));
  x = fmaxf(x, dppmov<0x4E>(x));
  x = fmaxf(x, dppmov<0x124>(x));
  x = fmaxf(x, dppmov<0x128>(x));
  return x;
}
__device__ __forceinline__ float red16_sum(float x){
  x += dppmov<0xB1>(x);
  x += dppmov<0x4E>(x);
  x += dppmov<0x124>(x);
  x += dppmov<0x128>(x);
  return x;
}

// C[m,n] = sum_k A[m,k] * B[n,k]  (both K-major bf16), 256 threads, waves 2x2.
template<int BM, int BN>
__device__ __forceinline__ void gemm_bt_core(
    const unsigned short* A, int lda,
    const unsigned short* B, int ldb,
    int K,
    f32x4 (&acc)[BM/32][BN/32],
    unsigned short* ldsA, unsigned short* ldsB)
{
  constexpr int TM = BM/32, TN = BN/32;
  const int tid  = threadIdx.x;
  const int lane = tid & 63;
  const int wave = tid >> 6;
  const int wm = wave >> 1, wn = wave & 1;
  const int fr = lane & 15;
  const int fk = (lane >> 4) << 3;
  const int sr = lane >> 2;
  const int sk = (lane & 3) << 3;

  for (int k0 = 0; k0 < K; k0 += 32){
    #pragma unroll
    for (int c = 0; c < BM/64; c++){
      int ch = c*4 + wave;
      async16(A + (long)(ch*16 + sr)*lda + (k0 + sk), ldsA + ch*512);
    }
    #pragma unroll
    for (int c = 0; c < BN/64; c++){
      int ch = c*4 + wave;
      async16(B + (long)(ch*16 + sr)*ldb + (k0 + sk), ldsB + ch*512);
    }
    __syncthreads();
    bf16x8 af[TM], bf[TN];
    #pragma unroll
    for (int i=0;i<TM;i++)
      af[i] = *(const bf16x8*)(ldsA + ((wm*TM*16) + i*16 + fr)*32 + fk);
    #pragma unroll
    for (int j=0;j<TN;j++)
      bf[j] = *(const bf16x8*)(ldsB + ((wn*TN*16) + j*16 + fr)*32 + fk);
    #pragma unroll
    for (int i=0;i<TM;i++)
      #pragma unroll
      for (int j=0;j<TN;j++)
        acc[i][j] = __builtin_amdgcn_mfma_f32_16x16x32_bf16(af[i], bf[j], acc[i][j], 0, 0, 0);
    __syncthreads();
  }
}

__device__ __forceinline__ float wred_sumf(float x){
  for(int o=32;o;o>>=1) x+=__shfl_xor(x,o); return x;
}

// ---------------- kernels ----------------

// vectorized f32->bf16 cast; also initializes the sinkhorn u/v vectors.
__global__ void f2b_multi(const float* __restrict__ x,
    const float* __restrict__ wq, const float* __restrict__ wk,
    const float* __restrict__ wv, const float* __restrict__ wo,
    unsigned short* __restrict__ out, float* __restrict__ uv)
{
  int i = blockIdx.x*256 + threadIdx.x;   // grid covers 2,097,152 threads x 4
  if (i < 8192) uv[i] = 1.0f;             // u, v
  int base = i << 2;
  const float* src;
  if (base < 4194304) src = x + base;
  else {
    int d = base - 4194304;
    int r = d >> 20, off = d & 1048575;
    src = (r==0 ? wq : (r==1 ? wk : (r==2 ? wv : wo))) + off;
  }
  float4 v = *(const float4*)src;
  ushort4 o;
  o.x = f2bf(v.x); o.y = f2bf(v.y); o.z = f2bf(v.z); o.w = f2bf(v.w);
  *(ushort4*)(out + base) = o;
}

// Q is pre-scaled by 0.125*log2e: the softmax then runs entirely in the
// exp2 domain (v_exp_f32 computes 2^x natively; saves the per-exp v_mul).
__global__ __launch_bounds__(256) void qkv_kernel(
    const unsigned short* __restrict__ xb,
    const unsigned short* __restrict__ Wqb, const float* __restrict__ bq,
    const unsigned short* __restrict__ Wkb, const float* __restrict__ bk,
    const unsigned short* __restrict__ Wvb, const float* __restrict__ bv,
    unsigned short* __restrict__ Qb, unsigned short* __restrict__ Kb,
    unsigned short* __restrict__ Vb)
{
  __shared__ unsigned short lds[(128+128)*32];
  int sel = blockIdx.y >> 3;
  int n0 = (blockIdx.y & 7) * 128;
  int m0 = blockIdx.x * 128;
  const unsigned short* W = sel==0 ? Wqb : (sel==1 ? Wkb : Wvb);
  const float* bias       = sel==0 ? bq  : (sel==1 ? bk  : bv);
  unsigned short* out     = sel==0 ? Qb  : (sel==1 ? Kb  : Vb);
  const float qs          = sel==0 ? 0.125f*LOG2E : 1.0f;
  f32x4 acc[4][4];
  f32x4 z = {0.f,0.f,0.f,0.f};
  for (int i=0;i<4;i++) for(int j=0;j<4;j++) acc[i][j] = z;
  gemm_bt_core<128,128>(xb + (long)m0*DMODEL, DMODEL, W + (long)n0*DMODEL, DMODEL,
                        DMODEL, acc, lds, lds + 128*32);
  int lane = threadIdx.x & 63, wave = threadIdx.x >> 6;
  int wm = wave>>1, wn = wave&1;
  int cr = (lane>>4)<<2, cc = lane & 15;
  for (int i=0;i<4;i++) for(int j=0;j<4;j++) for(int r=0;r<4;r++){
    int row = m0 + wm*64 + i*16 + cr + r;
    int col = n0 + wn*64 + j*16 + cc;
    out[(long)row*DMODEL + col] = f2bf((acc[i][j][r] + bias[col])*qs);
  }
}

// V transpose, bf16 -> f16 (attnA stages V with a raw copy)
__global__ void vtrans_kernel(const unsigned short* __restrict__ Vb,
                              unsigned short* __restrict__ Vt)
{
  __shared__ unsigned short t[32][33];
  int b = blockIdx.z, i0 = blockIdx.x*32, e0 = blockIdx.y*32;
  int tx = threadIdx.x, ty = threadIdx.y;
  for (int r=0;r<32;r+=8) t[ty+r][tx] = Vb[((long)b*NTOK + i0+ty+r)*DMODEL + e0+tx];
  __syncthreads();
  for (int r=0;r<32;r+=8)
    Vt[((long)b*DMODEL + e0+ty+r)*NTOK + i0+tx] = f2h(bf2f(t[tx][ty+r]));
}

// ---- split-K single-pass flash attention per (b,h,row-block,half).
// KVBLK=128, stride-136 Pt/Vtl, Kt source-swizzle (r12), DPP reductions
// (r13), exp2-domain softmax (r15). 2 barriers/iter (r16): the old 3rd
// barrier protected Pt, but Pt is wave-private (softmax writes and PV reads
// the same wave's 16 rows); Kt/Vtl hazards are covered by top+mid syncs.
// Unconditional rescale (defer-max spilled at this reg pressure, r10). ----
__global__ __launch_bounds__(512,4) void attnA_kernel(
    const unsigned short* __restrict__ Qb, const unsigned short* __restrict__ Kb,
    const unsigned short* __restrict__ Vt, const int* __restrict__ perm,
    const float* __restrict__ psc,
    float* __restrict__ mpart, float* __restrict__ lpart, float* __restrict__ Tpart,
    unsigned short* __restrict__ Opart)
{
  __shared__ unsigned short Kt[2*128*32];   // bf16 [kc][col][32]   16 KB
  __shared__ unsigned short Vtl[64*136];    // f16  [ocol][128+8]   17.4 KB
  __shared__ unsigned short Pt[128*136];    // f16  [row][128+8]    34.8 KB (wave-private rows)
  __shared__ unsigned short pbs[2048];      // 4 KB

  const int tid  = threadIdx.x;
  const int lane = tid & 63;
  const int wave = tid >> 6;              // 0..7, 16 rows each
  const int fr   = lane & 15;
  const int fkg  = lane >> 4;
  const int fk   = fkg << 3;
  const int cr   = fkg << 2;
  const int rw   = wave << 4;             // row base within 128-tile
  const int rt   = blockIdx.x >> 1;
  const int half = blockIdx.x & 1;
  const int m0   = rt * 128;
  const int h    = blockIdx.y;
  const int b    = blockIdx.z;

  // swizzled Kt read offset (matches the staging source swizzle)
  const int fks = (fkg ^ ((fr >> 1) & 3)) << 3;

  for (int i = tid; i < 2048; i += 512) pbs[i] = (unsigned short)perm[b*NTOK + i];

  bf16x8 qf[2];
  #pragma unroll
  for (int kc=0;kc<2;kc++)
    qf[kc] = *(const bf16x8*)(Qb + ((long)(b*NTOK + m0 + rw + fr))*DMODEL + h*HD + kc*32 + fk);

  const float asc = fabsf(psc[h])*LOG2E;
  __syncthreads();

  float prow[4];
  #pragma unroll
  for (int r=0;r<4;r++) prow[r] = (float)pbs[m0 + rw + cr + r];

  float mrow[4], lrow[4], Trow[4];
  #pragma unroll
  for (int r=0;r<4;r++){ mrow[r] = -1e30f; lrow[r] = 0.f; Trow[r] = 0.f; }
  f32x4 oacc[4];
  {
    f32x4 z = {0.f,0.f,0.f,0.f};
    for (int jj=0;jj<4;jj++) oacc[jj]=z;
  }

  for (int j2=0;j2<8;j2++){
    int j = half*8 + j2;       // 128-key tile index (0..15)
    __syncthreads();           // all PV reads of Kt/Vtl done before restage
    #pragma unroll
    for (int c=0;c<2;c++){     // K tile: 16 chunks of (16 cols x 32 k)
      int q = c*8 + wave;
      int kc = q >> 3, rb = (q & 7) * 16;
      // source k-selector swizzled: lane l stages kgrp (l&3)^((l>>3)&3)
      async16(Kb + ((long)(b*NTOK + j*128 + rb + (lane>>2)))*DMODEL + h*HD + kc*32
                 + ((((lane&3) ^ ((lane>>3)&3)))<<3),
              Kt + kc*4096 + rb*32);
    }
    {   // V tile: 64 ocols x 128 kv, f16 raw copy, 2 uint4 per thread
      int c = tid>>3, sg = tid&7;
      const unsigned short* vg = Vt + ((long)(b*DMODEL + h*HD + c))*NTOK + j*128 + sg*16;
      unsigned short* vl = Vtl + c*136 + sg*16;
      *(uint4*)(vl)   = *(const uint4*)(vg);
      *(uint4*)(vl+8) = *(const uint4*)(vg+8);
    }
    __syncthreads();           // staging visible to all waves

    f32x4 sacc[8];
    {
      f32x4 z = {0.f,0.f,0.f,0.f};
      for (int jj=0;jj<8;jj++) sacc[jj]=z;
    }
    #pragma unroll
    for (int kc=0;kc<2;kc++){
      bf16x8 bfr[8];
      #pragma unroll
      for (int jj=0;jj<8;jj++)
        bfr[jj] = *(const bf16x8*)(Kt + kc*4096 + (jj*16+fr)*32 + fks);
      #pragma unroll
      for (int jj=0;jj<8;jj++)
        sacc[jj] = __builtin_amdgcn_mfma_f32_16x16x32_bf16(qf[kc], bfr[jj], sacc[jj],0,0,0);
    }

    float pcol[8];
    #pragma unroll
    for (int jj=0;jj<8;jj++) pcol[jj] = (float)pbs[j*128 + jj*16 + fr];

    #pragma unroll
    for (int r=0;r<4;r++){
      float sv[8];
      float tm = -1e30f;
      #pragma unroll
      for (int jj=0;jj<8;jj++){
        sv[jj] = sacc[jj][r] - fabsf(prow[r]-pcol[jj])*asc;
        tm = fmaxf(tm, sv[jj]);
      }
      tm = red16_max(tm);
      float nm = fmaxf(mrow[r], tm);
      float alpha = fexp2(mrow[r] - nm);
      float lres = lrow[r]*alpha;
      Trow[r] = Trow[r]*alpha + (mrow[r]-nm)*lres;
      #pragma unroll
      for (int jc=0;jc<4;jc++) oacc[jc][r] *= alpha;
      float ts=0.f, tT=0.f;
      int prowbase = (rw + cr + r)*136;
      #pragma unroll
      for (int jj=0;jj<8;jj++){
        float d = sv[jj]-nm;
        float ev = fexp2(d);
        ts += ev; tT += ev*d;
        Pt[prowbase + jj*16 + fr] = f2h(ev);
      }
      ts = red16_sum(ts);
      tT = red16_sum(tT);
      lrow[r] = lres + ts;
      Trow[r] += tT;
      mrow[r] = nm;
    }
    // no barrier: Pt rows are wave-private (same-wave ds ordering suffices)
    #pragma unroll
    for (int kp=0;kp<4;kp++){
      f16x8 paf, pbf[4];
      paf = *(const f16x8*)(Pt + (rw+fr)*136 + kp*32 + fk);
      #pragma unroll
      for (int jj=0;jj<4;jj++) pbf[jj] = *(const f16x8*)(Vtl + (jj*16+fr)*136 + kp*32 + fk);
      #pragma unroll
      for (int jj=0;jj<4;jj++)
        oacc[jj] = __builtin_amdgcn_mfma_f32_16x16x32_f16(paf, pbf[jj], oacc[jj],0,0,0);
    }
  }

  // write partials (unnormalized O; m in log2 domain, T converted to nat)
  long pbase = ((long)(half*BATCH + b)*NHEADS + h)*NTOK;
  #pragma unroll
  for (int jj=0;jj<4;jj++)
    #pragma unroll
    for (int r=0;r<4;r++){
      int row = m0 + rw + cr + r;
      Opart[(pbase + row)*HD + jj*16 + fr] = f2bf(oacc[jj][r]);
    }
  if (fr == 0){
    #pragma unroll
    for (int r=0;r<4;r++){
      int row = m0 + rw + cr + r;
      mpart[pbase + row] = mrow[r];
      lpart[pbase + row] = lrow[r];
      Tpart[pbase + row] = Trow[r]*LN2;
    }
  }
}

// ---- merge the two key-halves: O -> Ob (normalized bf16), m/il/entropy.
// m values are in log2 domain (exp2 softmax); T already natural.
// r16: one block handles its 4 rows for ALL heads (16x fewer blocks). ----
__global__ __launch_bounds__(256) void merge_kernel(
    const float* __restrict__ mpart, const float* __restrict__ lpart,
    const float* __restrict__ Tpart, const unsigned short* __restrict__ Opart,
    unsigned short* __restrict__ Ob, float* __restrict__ mbuf,
    float* __restrict__ ilbuf, float* __restrict__ entb)
{
  int tid = threadIdx.x;
  int row = blockIdx.x*4 + (tid>>6);
  int b = blockIdx.y;
  int col = tid & 63;
  for (int h = 0; h < NHEADS; h++){
    long o1 = ((long)(0*BATCH + b)*NHEADS + h)*NTOK + row;
    long o2 = ((long)(1*BATCH + b)*NHEADS + h)*NTOK + row;
    float m1 = mpart[o1], m2 = mpart[o2];
    float l1 = lpart[o1], l2 = lpart[o2];
    float m = fmaxf(m1, m2);
    float e1 = fexp2(m1-m), e2 = fexp2(m2-m);
    float l = l1*e1 + l2*e2;
    float il = 1.0f/l;
    float Ov = (bf2f(Opart[o1*HD + col])*e1 + bf2f(Opart[o2*HD + col])*e2)*il;
    Ob[((long)(b*NTOK + row))*DMODEL + h*HD + col] = f2bf(Ov);
    if (col == 0){
      float T = e1*(Tpart[o1] + (m1-m)*LN2*l1) + e2*(Tpart[o2] + (m2-m)*LN2*l2);
      long off = ((long)(b*NHEADS+h))*NTOK + row;
      mbuf[off] = m; ilbuf[off] = il;
      entb[off] = T*il - __logf(l);   // = sum a*ln(a)
    }
  }
}

// ---- recompute QK^T per (b, 64-row x 128-col tile), 512 threads (2x4 waves).
// K-tile staged via global_load_lds with source k-swizzle, double-buffered
// across the head loop. exp2-domain softmax. r16: avg f32 output dropped --
// argmax reads the f16 avgH (quantization << existing bf16-QK^T noise). ----
__global__ __launch_bounds__(512,4) void avgP_kernel(
    const unsigned short* __restrict__ Qb, const unsigned short* __restrict__ Kb,
    const int* __restrict__ perm, const float* __restrict__ psc,
    const float* __restrict__ mbuf, const float* __restrict__ ilbuf,
    unsigned short* __restrict__ avgH, unsigned short* __restrict__ avgT)
{
  __shared__ unsigned short Kt[2][8192];   // 32 KB dbuf K tile (also T overlay)
  __shared__ float sm[NHEADS*64];          // [h][row] running max (4 KB)
  __shared__ float si[NHEADS*64];          // [h][row] 1/l (4 KB)
  __shared__ float sasc[NHEADS];

  // 2D XCD swizzle: XCD owns a 16-rowtile x 8-coltile quadrant of one batch
  const int bid = blockIdx.x;              // 1024 blocks
  const int xcd = bid & 7, idx = bid >> 3; // idx 0..127
  const int b   = xcd >> 2;
  const int qy  = (xcd >> 1) & 1, qx = xcd & 1;
  const int ydim = qy*16 + (idx >> 3);     // 0..31 (64-row tiles)
  const int xdim = qx*8  + (idx & 7);      // 0..15 (128-col tiles)
  const int m0   = ydim * 64;
  const int colb = xdim * 128;

  const int tid  = threadIdx.x;
  const int lane = tid & 63;
  const int wave = tid >> 6;               // 0..7, grid 2x4
  const int wr = wave >> 2, wc = wave & 3; // wave tile: 32 rows x 32 cols
  const int rw = wr*32, cb = wc*32;
  const int fr = lane & 15;
  const int fk = (lane >> 4) << 3;
  const int cr = (lane >> 4) << 2;
  const int cc = lane & 15;
  const int sr = lane >> 2;

  // swizzled Kt read offset (matches the staging source swizzle)
  const int fks = (((lane >> 4) ^ ((fr >> 1) & 3)) << 3);

  // per-thread staging slots (cid = q*8 + wave covers 16 chunks of 16colsx32k)
  const unsigned short* kgp[2];
  int ldsoff[2];
  #pragma unroll
  for (int q=0;q<2;q++){
    int cid = q*8 + wave;
    int kc = cid >> 3, ch = cid & 7;
    kgp[q] = Kb + ((long)(b*NTOK + colb + ch*16 + sr))*DMODEL + kc*32
               + ((((lane&3) ^ ((lane>>3)&3)))<<3);
    ldsoff[q] = kc*4096 + ch*512;
  }

  // stage (m, 1/l) for all heads x 64 rows, and |psc|*log2e
  for (int e = tid; e < NHEADS*64; e += 512){
    int h = e >> 6, r = e & 63;
    long off = ((long)(b*NHEADS + h))*NTOK + m0 + r;
    sm[e] = mbuf[off];
    si[e] = ilbuf[off];
  }
  if (tid < NHEADS) sasc[tid] = fabsf(psc[tid])*LOG2E;

  // permutation values (head-invariant)
  float prw[8];
  #pragma unroll
  for (int i=0;i<2;i++)
    #pragma unroll
    for (int r=0;r<4;r++)
      prw[i*4+r] = (float)perm[b*NTOK + m0 + rw + i*16 + cr + r];
  float pcl[2];
  #pragma unroll
  for (int j=0;j<2;j++)
    pcl[j] = (float)perm[b*NTOK + colb + cb + j*16 + cc];

  // Q fragment base pointers (per-lane 16B frags, L2-resident re-reads)
  const unsigned short* qp[2];
  #pragma unroll
  for (int i=0;i<2;i++)
    qp[i] = Qb + ((long)(b*NTOK + m0 + rw + i*16 + fr))*DMODEL + fk;

  float aacc[2][2][4];
  #pragma unroll
  for (int i=0;i<2;i++) for (int j=0;j<2;j++) for (int r=0;r<4;r++) aacc[i][j][r]=0.f;

  // prologue: stage head 0
  #pragma unroll
  for (int q=0;q<2;q++) async16(kgp[q], &Kt[0][0] + ldsoff[q]);
  __syncthreads();   // drains stage(h0); sm/si visible

  unsigned short* curb = &Kt[0][0];
  unsigned short* nxtb = &Kt[1][0];

  #pragma unroll 2
  for (int h=0; h<NHEADS; h++){
    if (h < NHEADS-1){   // stage next head's K tile (overlaps compute below)
      #pragma unroll
      for (int q=0;q<2;q++) async16(kgp[q] + (h+1)*HD, nxtb + ldsoff[q]);
    }
    // Q fragments for this head
    bf16x8 qf[2][2];
    #pragma unroll
    for (int i=0;i<2;i++)
      #pragma unroll
      for (int kc=0;kc<2;kc++)
        qf[i][kc] = *(const bf16x8*)(qp[i] + h*HD + kc*32);

    f32x4 acc[2][2];
    {
      f32x4 z = {0.f,0.f,0.f,0.f};
      acc[0][0]=z; acc[0][1]=z; acc[1][0]=z; acc[1][1]=z;
    }
    #pragma unroll
    for (int kc=0;kc<2;kc++){
      bf16x8 bfr[2];
      #pragma unroll
      for (int j=0;j<2;j++)
        bfr[j] = *(const bf16x8*)(curb + kc*4096 + ((cb>>4) + j)*512 + fr*32 + fks);
      #pragma unroll
      for (int i=0;i<2;i++)
        #pragma unroll
        for (int j=0;j<2;j++)
          acc[i][j] = __builtin_amdgcn_mfma_f32_16x16x32_bf16(qf[i][kc], bfr[j], acc[i][j],0,0,0);
    }
    const float asc = sasc[h];
    #pragma unroll
    for (int i=0;i<2;i++)
      #pragma unroll
      for (int r=0;r<4;r++){
        int rl = rw + i*16 + cr + r;
        float mh = sm[h*64 + rl];
        float ih = si[h*64 + rl];
        #pragma unroll
        for (int j=0;j<2;j++){
          float sv = acc[i][j][r] - fabsf(prw[i*4+r]-pcl[j])*asc;
          aacc[i][j][r] += fexp2(sv - mh) * ih;
        }
      }
    __syncthreads();   // drain stage(h+1) into nxtb; protect curb for reuse
    unsigned short* t = curb; curb = nxtb; nxtb = t;
  }

  // powered epilogue + stores (avgH f16 row-major, LDS-staged transpose).
  // ^10 via exp2(10*log2 x). T overlays the dead K buffers.
  unsigned short* T = &Kt[0][0];
  #pragma unroll
  for (int i=0;i<2;i++)
    #pragma unroll
    for (int j=0;j<2;j++)
      #pragma unroll
      for (int r=0;r<4;r++){
        float pw = fexp2(flog2(aacc[i][j][r]*0.0625f + EPSF)*10.0f);
        int rl = rw + i*16 + cr + r;      // 0..63
        int cl = cb + j*16 + cc;          // 0..127
        long off = ((long)(b*NTOK + m0 + rl))*NTOK + colb + cl;
        unsigned short hv = f2h(pw);
        avgH[off] = hv;
        T[cl*72 + rl] = hv;
      }
  __syncthreads();
  {   // coalesced transposed write: thread t -> col (t>>2), 16-row quarter
    int c = tid >> 2, sg = tid & 3;
    uint4* dst = (uint4*)(avgT + ((long)(b*NTOK + colb + c))*NTOK + m0 + sg*16);
    const unsigned short* src = T + c*72 + sg*16;
    dst[0] = *(const uint4*)(src);
    dst[1] = *(const uint4*)(src + 8);
  }
}

// y_i = y_i / (y_i * (M[i,:]. x) + eps)  -- f16 matrix, f32 u/v, wave per row
__global__ __launch_bounds__(256) void sink_phase_h(const unsigned short* __restrict__ M,
    const float* __restrict__ x, float* __restrict__ y)
{
  int b = blockIdx.y, tid = threadIdx.x;
  int wave = tid >> 6, lane = tid & 63;
  int i = blockIdx.x*4 + wave;
  const unsigned short* row = M + ((long)b*NTOK + i)*NTOK;
  const float* xb = x + b*NTOK;
  float s0 = 0.f, s1 = 0.f;
  #pragma unroll
  for (int k=0;k<4;k++){
    int j = k*512 + lane*8;
    f16x8 mv = *(const f16x8*)(row + j);
    float4 x0 = *(const float4*)(xb + j);
    float4 x1 = *(const float4*)(xb + j + 4);
    s0 += (float)mv[0]*x0.x + (float)mv[2]*x0.z + (float)mv[4]*x1.x + (float)mv[6]*x1.z;
    s1 += (float)mv[1]*x0.y + (float)mv[3]*x0.w + (float)mv[5]*x1.y + (float)mv[7]*x1.w;
  }
  float s = wred_sumf(s0 + s1);
  if (lane == 0){
    float yi = y[b*NTOK + i];
    y[b*NTOK + i] = yi / (yi*s + EPSF);
  }
}

// argmax over P[i,:]*v using the f16 avgH (quantization << bf16 QK^T noise)
__global__ __launch_bounds__(256) void argmax_kernel(const unsigned short* __restrict__ P,
    const float* __restrict__ v, const int* __restrict__ perm,
    float* __restrict__ dout_perm)
{
  int b = blockIdx.y, tid = threadIdx.x;
  int wave = tid >> 6, lane = tid & 63;
  int i = blockIdx.x*4 + wave;
  const unsigned short* row = P + ((long)b*NTOK + i)*NTOK;
  const float* vb = v + b*NTOK;
  float bv = -1.0f; int bj = 0;
  #pragma unroll
  for (int k=0;k<4;k++){
    int j0 = k*512 + lane*8;
    f16x8 mv = *(const f16x8*)(row + j0);
    #pragma unroll
    for (int e=0;e<8;e++){
      float val = (float)mv[e]*vb[j0+e];
      if (val>bv){ bv=val; bj=j0+e; }
    }
  }
  for (int o=32;o;o>>=1){
    float ov=__shfl_xor(bv,o); int oj=__shfl_xor(bj,o);
    if (ov>bv || (ov==bv && oj<bj)){bv=ov;bj=oj;}
  }
  if (lane == 0)
    dout_perm[b*NTOK + i] = (float)perm[b*NTOK + bj];
}

__global__ __launch_bounds__(256) void out_kernel(
    const unsigned short* __restrict__ Ob, const unsigned short* __restrict__ Wob,
    const float* __restrict__ bo, float* __restrict__ dout)
{
  __shared__ unsigned short lds[(128+128)*32];
  int m0 = blockIdx.x*128, n0 = blockIdx.y*128;
  f32x4 acc[4][4];
  f32x4 z = {0.f,0.f,0.f,0.f};
  for (int i=0;i<4;i++) for(int j=0;j<4;j++) acc[i][j] = z;
  gemm_bt_core<128,128>(Ob + (long)m0*DMODEL, DMODEL, Wob + (long)n0*DMODEL, DMODEL,
                        DMODEL, acc, lds, lds + 128*32);
  int lane = threadIdx.x & 63, wave = threadIdx.x >> 6;
  int wm = wave>>1, wn = wave&1;
  int cr = (lane>>4)<<2, cc = lane & 15;
  for (int i=0;i<4;i++) for(int j=0;j<4;j++) for(int r=0;r<4;r++){
    int row = m0 + wm*64 + i*16 + cr + r;
    int col = n0 + wn*64 + j*16 + cc;
    dout[(long)row*DMODEL + col] = acc[i][j][r] + bo[col];
  }
}

__global__ void cert_kernel(const float* __restrict__ cert,
    const float* __restrict__ ctemp, const float* __restrict__ entb,
    float* __restrict__ dout_cert)
{
  int idx = blockIdx.x*256+threadIdx.x;
  if (idx >= BATCH*NTOK) return;
  int b = idx >> 11, row = idx & 2047;
  float s = 0.f;
  #pragma unroll
  for (int h=0; h<NHEADS; h++) s += entb[((long)(b*NHEADS+h))*NTOK + row];
  float ent = -s * (1.0f/16.0f);
  float ct = ctemp[0];
  float arg = ct * (logf((float)NTOK) - ent);
  float upd = 1.0f/(1.0f+expf(-arg));
  dout_cert[idx] = fmaxf(cert[idx], upd);
}

extern "C" void kernel_launch(void* const* d_in, const int* in_sizes, int n_in,
                              void* d_out, int out_size, void* d_ws, size_t ws_size,
                              hipStream_t stream)
{
  const float* x    = (const float*)d_in[0];
  const float* cert = (const float*)d_in[1];
  const int*   perm = (const int*)d_in[2];
  const float* Wq   = (const float*)d_in[3];
  const float* bq   = (const float*)d_in[4];
  const float* Wk   = (const float*)d_in[5];
  const float* bk   = (const float*)d_in[6];
  const float* Wv   = (const float*)d_in[7];
  const float* bv   = (const float*)d_in[8];
  const float* Wo   = (const float*)d_in[9];
  const float* bo   = (const float*)d_in[10];
  const float* psc  = (const float*)d_in[11];
  const float* ctmp = (const float*)d_in[12];
  float* dout = (float*)d_out;

  // layout: f32 u/v, f32 arrays, split-K partials, bf16/f16 region
  float* u     = (float*)d_ws;                          // 4096
  float* v     = u + 4096;                              // 4096
  float* avg   = v + 4096;                              // 8,388,608 f32 (unused, kept for layout)
  float* mbuf  = avg   + 8388608;                       // 65,536
  float* ilbuf = mbuf  + 65536;                         // 65,536
  float* entb  = ilbuf + 65536;                         // 65,536
  float* mpart = entb  + 65536;                         // 131,072 (2 halves)
  float* lpart = mpart + 131072;                        // 131,072
  float* Tpart = lpart + 131072;                        // 131,072
  unsigned short* Opart = (unsigned short*)(Tpart + 131072);  // 8,388,608 bf16
  unsigned short* xb  = Opart + 8388608;                // 4,194,304
  unsigned short* Wqb = xb  + 4194304;
  unsigned short* Wkb = Wqb + 1048576;
  unsigned short* Wvb = Wkb + 1048576;
  unsigned short* Wob = Wvb + 1048576;
  unsigned short* Qb  = Wob + 1048576;                  // 4,194,304 each
  unsigned short* Kb  = Qb  + 4194304;
  unsigned short* Vb  = Kb  + 4194304;
  unsigned short* Vt  = Vb  + 4194304;                  // f16 after vtrans
  unsigned short* Ob  = Vt  + 4194304;                  // 4,194,304
  // overlays (regions dead by the time these are written):
  unsigned short* avgH = Opart;                         // f16 row-major (Opart dead after merge)
  unsigned short* avgT = Vb;                            // f16 transposed (Vb+Vt dead after attnA)

  f2b_multi<<<dim3(8192),256,0,stream>>>(x, Wq, Wk, Wv, Wo, xb, u);

  qkv_kernel<<<dim3(32,24),256,0,stream>>>(xb, Wqb,bq, Wkb,bk, Wvb,bv, Qb,Kb,Vb);
  vtrans_kernel<<<dim3(64,32,2), dim3(32,8),0,stream>>>(Vb, Vt);

  attnA_kernel<<<dim3(32,NHEADS,2),512,0,stream>>>(Qb, Kb, Vt, perm, psc,
      mpart, lpart, Tpart, Opart);
  merge_kernel<<<dim3(512,2),256,0,stream>>>(mpart, lpart, Tpart, Opart,
      Ob, mbuf, ilbuf, entb);
  avgP_kernel<<<dim3(1024),512,0,stream>>>(Qb, Kb, perm, psc, mbuf, ilbuf,
      avgH, avgT);

  for (int it=0; it<10; it++){
    sink_phase_h<<<dim3(512,2),256,0,stream>>>(avgH, v, u);
    sink_phase_h<<<dim3(512,2),256,0,stream>>>(avgT, u, v);
  }
  argmax_kernel<<<dim3(512,2),256,0,stream>>>(avgH, v, perm, dout + 4194304 + 4096);

  out_kernel <<<dim3(32,8),256,0,stream>>>(Ob, Wob, bo, dout);
  cert_kernel<<<dim3(16), 256,0,stream>>>(cert, ctmp, entb, dout + 4194304);
}

// Round 17
// 417.435 us; speedup vs baseline: 1.0451x; 1.0451x over previous
//
#include <hip/hip_runtime.h>
#include <cstdint>

#define NTOK 2048
#define DMODEL 1024
#define NHEADS 16
#define HD 64
#define BATCH 2
#define EPSF 1e-10f
#define LOG2E 1.44269504088896340736f
#define LN2   0.69314718055994530942f

typedef __attribute__((ext_vector_type(8))) short bf16x8;
typedef __attribute__((ext_vector_type(8))) _Float16 f16x8;
typedef __attribute__((ext_vector_type(4))) float f32x4;

__device__ __forceinline__ float bf2f(unsigned short u){
  union { unsigned int i; float f; } c; c.i = ((unsigned int)u) << 16; return c.f;
}
__device__ __forceinline__ unsigned short f2bf(float f){
  union { float f; unsigned int u; } c; c.f = f;
  unsigned int u = c.u;
  unsigned int r = (u + 0x7FFFu + ((u >> 16) & 1u)) >> 16;
  return (unsigned short)r;
}
__device__ __forceinline__ unsigned short f2h(float f){
  union { _Float16 h; unsigned short u; } c; c.h = (_Float16)f; return c.u;
}
__device__ __forceinline__ float h2f(unsigned short u){
  union { unsigned short u; _Float16 h; } c; c.u = u; return (float)c.h;
}

// bare v_exp_f32 / v_log_f32 (2^x, log2 x) -- avoids __expf's implicit
// *log2e v_mul. All softmax inputs are pre-scaled into log2 domain.
__device__ __forceinline__ float fexp2(float x){
#if __has_builtin(__builtin_amdgcn_exp2f)
  return __builtin_amdgcn_exp2f(x);
#else
  return exp2f(x);
#endif
}
__device__ __forceinline__ float flog2(float x){
#if __has_builtin(__builtin_amdgcn_logf)
  return __builtin_amdgcn_logf(x);
#else
  return __log2f(x);
#endif
}

__device__ __forceinline__ void async16(const unsigned short* g, unsigned short* lds_base){
  __builtin_amdgcn_global_load_lds((const __attribute__((address_space(1))) unsigned int*)g,
                                   (__attribute__((address_space(3))) unsigned int*)lds_base,
                                   16, 0, 0);
}

// DPP 16-lane reductions (VALU pipe; replaces ds-pipe __shfl_xor chains).
template<int CTRL>
__device__ __forceinline__ float dppmov(float x){
  union { float f; int i; } a, r;
  a.f = x;
  r.i = __builtin_amdgcn_update_dpp(0, a.i, CTRL, 0xF, 0xF, true);
  return r.f;
}
__device__ __forceinline__ float red16_max(float x){
  x = fmaxf(x, dppmov<0xB1>(x));
  x = fmaxf(x, dppmov<0x4E>(x));
  x = fmaxf(x, dppmov<0x124>(x));
  x = fmaxf(x, dppmov<0x128>(x));
  return x;
}
__device__ __forceinline__ float red16_sum(float x){
  x += dppmov<0xB1>(x);
  x += dppmov<0x4E>(x);
  x += dppmov<0x124>(x);
  x += dppmov<0x128>(x);
  return x;
}

// C[m,n] = sum_k A[m,k] * B[n,k]  (both K-major bf16), 256 threads, waves 2x2.
template<int BM, int BN>
__device__ __forceinline__ void gemm_bt_core(
    const unsigned short* A, int lda,
    const unsigned short* B, int ldb,
    int K,
    f32x4 (&acc)[BM/32][BN/32],
    unsigned short* ldsA, unsigned short* ldsB)
{
  constexpr int TM = BM/32, TN = BN/32;
  const int tid  = threadIdx.x;
  const int lane = tid & 63;
  const int wave = tid >> 6;
  const int wm = wave >> 1, wn = wave & 1;
  const int fr = lane & 15;
  const int fk = (lane >> 4) << 3;
  const int sr = lane >> 2;
  const int sk = (lane & 3) << 3;

  for (int k0 = 0; k0 < K; k0 += 32){
    #pragma unroll
    for (int c = 0; c < BM/64; c++){
      int ch = c*4 + wave;
      async16(A + (long)(ch*16 + sr)*lda + (k0 + sk), ldsA + ch*512);
    }
    #pragma unroll
    for (int c = 0; c < BN/64; c++){
      int ch = c*4 + wave;
      async16(B + (long)(ch*16 + sr)*ldb + (k0 + sk), ldsB + ch*512);
    }
    __syncthreads();
    bf16x8 af[TM], bf[TN];
    #pragma unroll
    for (int i=0;i<TM;i++)
      af[i] = *(const bf16x8*)(ldsA + ((wm*TM*16) + i*16 + fr)*32 + fk);
    #pragma unroll
    for (int j=0;j<TN;j++)
      bf[j] = *(const bf16x8*)(ldsB + ((wn*TN*16) + j*16 + fr)*32 + fk);
    #pragma unroll
    for (int i=0;i<TM;i++)
      #pragma unroll
      for (int j=0;j<TN;j++)
        acc[i][j] = __builtin_amdgcn_mfma_f32_16x16x32_bf16(af[i], bf[j], acc[i][j], 0, 0, 0);
    __syncthreads();
  }
}

__device__ __forceinline__ float wred_sumf(float x){
  for(int o=32;o;o>>=1) x+=__shfl_xor(x,o); return x;
}

// ---------------- kernels ----------------

// vectorized f32->bf16 cast; also initializes the sinkhorn u/v vectors.
__global__ void f2b_multi(const float* __restrict__ x,
    const float* __restrict__ wq, const float* __restrict__ wk,
    const float* __restrict__ wv, const float* __restrict__ wo,
    unsigned short* __restrict__ out, float* __restrict__ uv)
{
  int i = blockIdx.x*256 + threadIdx.x;   // grid covers 2,097,152 threads x 4
  if (i < 8192) uv[i] = 1.0f;             // u, v
  int base = i << 2;
  const float* src;
  if (base < 4194304) src = x + base;
  else {
    int d = base - 4194304;
    int r = d >> 20, off = d & 1048575;
    src = (r==0 ? wq : (r==1 ? wk : (r==2 ? wv : wo))) + off;
  }
  float4 v = *(const float4*)src;
  ushort4 o;
  o.x = f2bf(v.x); o.y = f2bf(v.y); o.z = f2bf(v.z); o.w = f2bf(v.w);
  *(ushort4*)(out + base) = o;
}

// Q is pre-scaled by 0.125*log2e: the softmax then runs entirely in the
// exp2 domain (v_exp_f32 computes 2^x natively; saves the per-exp v_mul).
__global__ __launch_bounds__(256) void qkv_kernel(
    const unsigned short* __restrict__ xb,
    const unsigned short* __restrict__ Wqb, const float* __restrict__ bq,
    const unsigned short* __restrict__ Wkb, const float* __restrict__ bk,
    const unsigned short* __restrict__ Wvb, const float* __restrict__ bv,
    unsigned short* __restrict__ Qb, unsigned short* __restrict__ Kb,
    unsigned short* __restrict__ Vb)
{
  __shared__ unsigned short lds[(128+128)*32];
  int sel = blockIdx.y >> 3;
  int n0 = (blockIdx.y & 7) * 128;
  int m0 = blockIdx.x * 128;
  const unsigned short* W = sel==0 ? Wqb : (sel==1 ? Wkb : Wvb);
  const float* bias       = sel==0 ? bq  : (sel==1 ? bk  : bv);
  unsigned short* out     = sel==0 ? Qb  : (sel==1 ? Kb  : Vb);
  const float qs          = sel==0 ? 0.125f*LOG2E : 1.0f;
  f32x4 acc[4][4];
  f32x4 z = {0.f,0.f,0.f,0.f};
  for (int i=0;i<4;i++) for(int j=0;j<4;j++) acc[i][j] = z;
  gemm_bt_core<128,128>(xb + (long)m0*DMODEL, DMODEL, W + (long)n0*DMODEL, DMODEL,
                        DMODEL, acc, lds, lds + 128*32);
  int lane = threadIdx.x & 63, wave = threadIdx.x >> 6;
  int wm = wave>>1, wn = wave&1;
  int cr = (lane>>4)<<2, cc = lane & 15;
  for (int i=0;i<4;i++) for(int j=0;j<4;j++) for(int r=0;r<4;r++){
    int row = m0 + wm*64 + i*16 + cr + r;
    int col = n0 + wn*64 + j*16 + cc;
    out[(long)row*DMODEL + col] = f2bf((acc[i][j][r] + bias[col])*qs);
  }
}

// V transpose, bf16 -> f16 (attnA stages V with a raw copy)
__global__ void vtrans_kernel(const unsigned short* __restrict__ Vb,
                              unsigned short* __restrict__ Vt)
{
  __shared__ unsigned short t[32][33];
  int b = blockIdx.z, i0 = blockIdx.x*32, e0 = blockIdx.y*32;
  int tx = threadIdx.x, ty = threadIdx.y;
  for (int r=0;r<32;r+=8) t[ty+r][tx] = Vb[((long)b*NTOK + i0+ty+r)*DMODEL + e0+tx];
  __syncthreads();
  for (int r=0;r<32;r+=8)
    Vt[((long)b*DMODEL + e0+ty+r)*NTOK + i0+tx] = f2h(bf2f(t[tx][ty+r]));
}

// ---- split-K single-pass flash attention per (b,h,row-block,half).
// KVBLK=128, stride-136 Pt/Vtl, Kt source-swizzle (r12), DPP reductions
// (r13), exp2-domain softmax (r15). 3 barriers/iter: r16 removed the 3rd
// (Pt is wave-private, correctness held) but without that scheduling fence
// the compiler interleaved PV with next-iter staging -> 107 MB scratch
// spill (WRITE 20->127 MB, +17 us). The barrier stays as a pressure fence.
// Unconditional rescale (defer-max spilled at this reg pressure, r10). ----
__global__ __launch_bounds__(512,4) void attnA_kernel(
    const unsigned short* __restrict__ Qb, const unsigned short* __restrict__ Kb,
    const unsigned short* __restrict__ Vt, const int* __restrict__ perm,
    const float* __restrict__ psc,
    float* __restrict__ mpart, float* __restrict__ lpart, float* __restrict__ Tpart,
    unsigned short* __restrict__ Opart)
{
  __shared__ unsigned short Kt[2*128*32];   // bf16 [kc][col][32]   16 KB
  __shared__ unsigned short Vtl[64*136];    // f16  [ocol][128+8]   17.4 KB
  __shared__ unsigned short Pt[128*136];    // f16  [row][128+8]    34.8 KB
  __shared__ unsigned short pbs[2048];      // 4 KB

  const int tid  = threadIdx.x;
  const int lane = tid & 63;
  const int wave = tid >> 6;              // 0..7, 16 rows each
  const int fr   = lane & 15;
  const int fkg  = lane >> 4;
  const int fk   = fkg << 3;
  const int cr   = fkg << 2;
  const int rw   = wave << 4;             // row base within 128-tile
  const int rt   = blockIdx.x >> 1;
  const int half = blockIdx.x & 1;
  const int m0   = rt * 128;
  const int h    = blockIdx.y;
  const int b    = blockIdx.z;

  // swizzled Kt read offset (matches the staging source swizzle)
  const int fks = (fkg ^ ((fr >> 1) & 3)) << 3;

  for (int i = tid; i < 2048; i += 512) pbs[i] = (unsigned short)perm[b*NTOK + i];

  bf16x8 qf[2];
  #pragma unroll
  for (int kc=0;kc<2;kc++)
    qf[kc] = *(const bf16x8*)(Qb + ((long)(b*NTOK + m0 + rw + fr))*DMODEL + h*HD + kc*32 + fk);

  const float asc = fabsf(psc[h])*LOG2E;
  __syncthreads();

  float prow[4];
  #pragma unroll
  for (int r=0;r<4;r++) prow[r] = (float)pbs[m0 + rw + cr + r];

  float mrow[4], lrow[4], Trow[4];
  #pragma unroll
  for (int r=0;r<4;r++){ mrow[r] = -1e30f; lrow[r] = 0.f; Trow[r] = 0.f; }
  f32x4 oacc[4];
  {
    f32x4 z = {0.f,0.f,0.f,0.f};
    for (int jj=0;jj<4;jj++) oacc[jj]=z;
  }

  for (int j2=0;j2<8;j2++){
    int j = half*8 + j2;       // 128-key tile index (0..15)
    __syncthreads();           // all PV reads of Kt/Vtl done before restage
    #pragma unroll
    for (int c=0;c<2;c++){     // K tile: 16 chunks of (16 cols x 32 k)
      int q = c*8 + wave;
      int kc = q >> 3, rb = (q & 7) * 16;
      // source k-selector swizzled: lane l stages kgrp (l&3)^((l>>3)&3)
      async16(Kb + ((long)(b*NTOK + j*128 + rb + (lane>>2)))*DMODEL + h*HD + kc*32
                 + ((((lane&3) ^ ((lane>>3)&3)))<<3),
              Kt + kc*4096 + rb*32);
    }
    {   // V tile: 64 ocols x 128 kv, f16 raw copy, 2 uint4 per thread
      int c = tid>>3, sg = tid&7;
      const unsigned short* vg = Vt + ((long)(b*DMODEL + h*HD + c))*NTOK + j*128 + sg*16;
      unsigned short* vl = Vtl + c*136 + sg*16;
      *(uint4*)(vl)   = *(const uint4*)(vg);
      *(uint4*)(vl+8) = *(const uint4*)(vg+8);
    }
    __syncthreads();           // staging visible to all waves

    f32x4 sacc[8];
    {
      f32x4 z = {0.f,0.f,0.f,0.f};
      for (int jj=0;jj<8;jj++) sacc[jj]=z;
    }
    #pragma unroll
    for (int kc=0;kc<2;kc++){
      bf16x8 bfr[8];
      #pragma unroll
      for (int jj=0;jj<8;jj++)
        bfr[jj] = *(const bf16x8*)(Kt + kc*4096 + (jj*16+fr)*32 + fks);
      #pragma unroll
      for (int jj=0;jj<8;jj++)
        sacc[jj] = __builtin_amdgcn_mfma_f32_16x16x32_bf16(qf[kc], bfr[jj], sacc[jj],0,0,0);
    }

    float pcol[8];
    #pragma unroll
    for (int jj=0;jj<8;jj++) pcol[jj] = (float)pbs[j*128 + jj*16 + fr];

    #pragma unroll
    for (int r=0;r<4;r++){
      float sv[8];
      float tm = -1e30f;
      #pragma unroll
      for (int jj=0;jj<8;jj++){
        sv[jj] = sacc[jj][r] - fabsf(prow[r]-pcol[jj])*asc;
        tm = fmaxf(tm, sv[jj]);
      }
      tm = red16_max(tm);
      float nm = fmaxf(mrow[r], tm);
      float alpha = fexp2(mrow[r] - nm);
      float lres = lrow[r]*alpha;
      Trow[r] = Trow[r]*alpha + (mrow[r]-nm)*lres;
      #pragma unroll
      for (int jc=0;jc<4;jc++) oacc[jc][r] *= alpha;
      float ts=0.f, tT=0.f;
      int prowbase = (rw + cr + r)*136;
      #pragma unroll
      for (int jj=0;jj<8;jj++){
        float d = sv[jj]-nm;
        float ev = fexp2(d);
        ts += ev; tT += ev*d;
        Pt[prowbase + jj*16 + fr] = f2h(ev);
      }
      ts = red16_sum(ts);
      tT = red16_sum(tT);
      lrow[r] = lres + ts;
      Trow[r] += tT;
      mrow[r] = nm;
    }
    __syncthreads();           // scheduling fence: keeps PV out of softmax's
                               // register window (r16: removing it spilled)
    #pragma unroll
    for (int kp=0;kp<4;kp++){
      f16x8 paf, pbf[4];
      paf = *(const f16x8*)(Pt + (rw+fr)*136 + kp*32 + fk);
      #pragma unroll
      for (int jj=0;jj<4;jj++) pbf[jj] = *(const f16x8*)(Vtl + (jj*16+fr)*136 + kp*32 + fk);
      #pragma unroll
      for (int jj=0;jj<4;jj++)
        oacc[jj] = __builtin_amdgcn_mfma_f32_16x16x32_f16(paf, pbf[jj], oacc[jj],0,0,0);
    }
  }

  // write partials (unnormalized O; m in log2 domain, T converted to nat)
  long pbase = ((long)(half*BATCH + b)*NHEADS + h)*NTOK;
  #pragma unroll
  for (int jj=0;jj<4;jj++)
    #pragma unroll
    for (int r=0;r<4;r++){
      int row = m0 + rw + cr + r;
      Opart[(pbase + row)*HD + jj*16 + fr] = f2bf(oacc[jj][r]);
    }
  if (fr == 0){
    #pragma unroll
    for (int r=0;r<4;r++){
      int row = m0 + rw + cr + r;
      mpart[pbase + row] = mrow[r];
      lpart[pbase + row] = lrow[r];
      Tpart[pbase + row] = Trow[r]*LN2;
    }
  }
}

// ---- merge the two key-halves: O -> Ob (normalized bf16), m/il/entropy.
// m values are in log2 domain (exp2 softmax); T already natural.
// One block handles its 4 rows for ALL heads (16x fewer blocks). ----
__global__ __launch_bounds__(256) void merge_kernel(
    const float* __restrict__ mpart, const float* __restrict__ lpart,
    const float* __restrict__ Tpart, const unsigned short* __restrict__ Opart,
    unsigned short* __restrict__ Ob, float* __restrict__ mbuf,
    float* __restrict__ ilbuf, float* __restrict__ entb)
{
  int tid = threadIdx.x;
  int row = blockIdx.x*4 + (tid>>6);
  int b = blockIdx.y;
  int col = tid & 63;
  for (int h = 0; h < NHEADS; h++){
    long o1 = ((long)(0*BATCH + b)*NHEADS + h)*NTOK + row;
    long o2 = ((long)(1*BATCH + b)*NHEADS + h)*NTOK + row;
    float m1 = mpart[o1], m2 = mpart[o2];
    float l1 = lpart[o1], l2 = lpart[o2];
    float m = fmaxf(m1, m2);
    float e1 = fexp2(m1-m), e2 = fexp2(m2-m);
    float l = l1*e1 + l2*e2;
    float il = 1.0f/l;
    float Ov = (bf2f(Opart[o1*HD + col])*e1 + bf2f(Opart[o2*HD + col])*e2)*il;
    Ob[((long)(b*NTOK + row))*DMODEL + h*HD + col] = f2bf(Ov);
    if (col == 0){
      float T = e1*(Tpart[o1] + (m1-m)*LN2*l1) + e2*(Tpart[o2] + (m2-m)*LN2*l2);
      long off = ((long)(b*NHEADS+h))*NTOK + row;
      mbuf[off] = m; ilbuf[off] = il;
      entb[off] = T*il - __logf(l);   // = sum a*ln(a)
    }
  }
}

// ---- recompute QK^T per (b, 64-row x 128-col tile), 512 threads (2x4 waves).
// K-tile staged via global_load_lds with source k-swizzle, double-buffered
// across the head loop. exp2-domain softmax. avg f32 output dropped --
// argmax reads the f16 avgH (quantization << existing bf16-QK^T noise). ----
__global__ __launch_bounds__(512,4) void avgP_kernel(
    const unsigned short* __restrict__ Qb, const unsigned short* __restrict__ Kb,
    const int* __restrict__ perm, const float* __restrict__ psc,
    const float* __restrict__ mbuf, const float* __restrict__ ilbuf,
    unsigned short* __restrict__ avgH, unsigned short* __restrict__ avgT)
{
  __shared__ unsigned short Kt[2][8192];   // 32 KB dbuf K tile (also T overlay)
  __shared__ float sm[NHEADS*64];          // [h][row] running max (4 KB)
  __shared__ float si[NHEADS*64];          // [h][row] 1/l (4 KB)
  __shared__ float sasc[NHEADS];

  // 2D XCD swizzle: XCD owns a 16-rowtile x 8-coltile quadrant of one batch
  const int bid = blockIdx.x;              // 1024 blocks
  const int xcd = bid & 7, idx = bid >> 3; // idx 0..127
  const int b   = xcd >> 2;
  const int qy  = (xcd >> 1) & 1, qx = xcd & 1;
  const int ydim = qy*16 + (idx >> 3);     // 0..31 (64-row tiles)
  const int xdim = qx*8  + (idx & 7);      // 0..15 (128-col tiles)
  const int m0   = ydim * 64;
  const int colb = xdim * 128;

  const int tid  = threadIdx.x;
  const int lane = tid & 63;
  const int wave = tid >> 6;               // 0..7, grid 2x4
  const int wr = wave >> 2, wc = wave & 3; // wave tile: 32 rows x 32 cols
  const int rw = wr*32, cb = wc*32;
  const int fr = lane & 15;
  const int fk = (lane >> 4) << 3;
  const int cr = (lane >> 4) << 2;
  const int cc = lane & 15;
  const int sr = lane >> 2;

  // swizzled Kt read offset (matches the staging source swizzle)
  const int fks = (((lane >> 4) ^ ((fr >> 1) & 3)) << 3);

  // per-thread staging slots (cid = q*8 + wave covers 16 chunks of 16colsx32k)
  const unsigned short* kgp[2];
  int ldsoff[2];
  #pragma unroll
  for (int q=0;q<2;q++){
    int cid = q*8 + wave;
    int kc = cid >> 3, ch = cid & 7;
    kgp[q] = Kb + ((long)(b*NTOK + colb + ch*16 + sr))*DMODEL + kc*32
               + ((((lane&3) ^ ((lane>>3)&3)))<<3);
    ldsoff[q] = kc*4096 + ch*512;
  }

  // stage (m, 1/l) for all heads x 64 rows, and |psc|*log2e
  for (int e = tid; e < NHEADS*64; e += 512){
    int h = e >> 6, r = e & 63;
    long off = ((long)(b*NHEADS + h))*NTOK + m0 + r;
    sm[e] = mbuf[off];
    si[e] = ilbuf[off];
  }
  if (tid < NHEADS) sasc[tid] = fabsf(psc[tid])*LOG2E;

  // permutation values (head-invariant)
  float prw[8];
  #pragma unroll
  for (int i=0;i<2;i++)
    #pragma unroll
    for (int r=0;r<4;r++)
      prw[i*4+r] = (float)perm[b*NTOK + m0 + rw + i*16 + cr + r];
  float pcl[2];
  #pragma unroll
  for (int j=0;j<2;j++)
    pcl[j] = (float)perm[b*NTOK + colb + cb + j*16 + cc];

  // Q fragment base pointers (per-lane 16B frags, L2-resident re-reads)
  const unsigned short* qp[2];
  #pragma unroll
  for (int i=0;i<2;i++)
    qp[i] = Qb + ((long)(b*NTOK + m0 + rw + i*16 + fr))*DMODEL + fk;

  float aacc[2][2][4];
  #pragma unroll
  for (int i=0;i<2;i++) for (int j=0;j<2;j++) for (int r=0;r<4;r++) aacc[i][j][r]=0.f;

  // prologue: stage head 0
  #pragma unroll
  for (int q=0;q<2;q++) async16(kgp[q], &Kt[0][0] + ldsoff[q]);
  __syncthreads();   // drains stage(h0); sm/si visible

  unsigned short* curb = &Kt[0][0];
  unsigned short* nxtb = &Kt[1][0];

  #pragma unroll 2
  for (int h=0; h<NHEADS; h++){
    if (h < NHEADS-1){   // stage next head's K tile (overlaps compute below)
      #pragma unroll
      for (int q=0;q<2;q++) async16(kgp[q] + (h+1)*HD, nxtb + ldsoff[q]);
    }
    // Q fragments for this head
    bf16x8 qf[2][2];
    #pragma unroll
    for (int i=0;i<2;i++)
      #pragma unroll
      for (int kc=0;kc<2;kc++)
        qf[i][kc] = *(const bf16x8*)(qp[i] + h*HD + kc*32);

    f32x4 acc[2][2];
    {
      f32x4 z = {0.f,0.f,0.f,0.f};
      acc[0][0]=z; acc[0][1]=z; acc[1][0]=z; acc[1][1]=z;
    }
    #pragma unroll
    for (int kc=0;kc<2;kc++){
      bf16x8 bfr[2];
      #pragma unroll
      for (int j=0;j<2;j++)
        bfr[j] = *(const bf16x8*)(curb + kc*4096 + ((cb>>4) + j)*512 + fr*32 + fks);
      #pragma unroll
      for (int i=0;i<2;i++)
        #pragma unroll
        for (int j=0;j<2;j++)
          acc[i][j] = __builtin_amdgcn_mfma_f32_16x16x32_bf16(qf[i][kc], bfr[j], acc[i][j],0,0,0);
    }
    const float asc = sasc[h];
    #pragma unroll
    for (int i=0;i<2;i++)
      #pragma unroll
      for (int r=0;r<4;r++){
        int rl = rw + i*16 + cr + r;
        float mh = sm[h*64 + rl];
        float ih = si[h*64 + rl];
        #pragma unroll
        for (int j=0;j<2;j++){
          float sv = acc[i][j][r] - fabsf(prw[i*4+r]-pcl[j])*asc;
          aacc[i][j][r] += fexp2(sv - mh) * ih;
        }
      }
    __syncthreads();   // drain stage(h+1) into nxtb; protect curb for reuse
    unsigned short* t = curb; curb = nxtb; nxtb = t;
  }

  // powered epilogue + stores (avgH f16 row-major, LDS-staged transpose).
  // ^10 via exp2(10*log2 x). T overlays the dead K buffers.
  unsigned short* T = &Kt[0][0];
  #pragma unroll
  for (int i=0;i<2;i++)
    #pragma unroll
    for (int j=0;j<2;j++)
      #pragma unroll
      for (int r=0;r<4;r++){
        float pw = fexp2(flog2(aacc[i][j][r]*0.0625f + EPSF)*10.0f);
        int rl = rw + i*16 + cr + r;      // 0..63
        int cl = cb + j*16 + cc;          // 0..127
        long off = ((long)(b*NTOK + m0 + rl))*NTOK + colb + cl;
        unsigned short hv = f2h(pw);
        avgH[off] = hv;
        T[cl*72 + rl] = hv;
      }
  __syncthreads();
  {   // coalesced transposed write: thread t -> col (t>>2), 16-row quarter
    int c = tid >> 2, sg = tid & 3;
    uint4* dst = (uint4*)(avgT + ((long)(b*NTOK + colb + c))*NTOK + m0 + sg*16);
    const unsigned short* src = T + c*72 + sg*16;
    dst[0] = *(const uint4*)(src);
    dst[1] = *(const uint4*)(src + 8);
  }
}

// y_i = y_i / (y_i * (M[i,:]. x) + eps)  -- f16 matrix, f32 u/v, wave per row
__global__ __launch_bounds__(256) void sink_phase_h(const unsigned short* __restrict__ M,
    const float* __restrict__ x, float* __restrict__ y)
{
  int b = blockIdx.y, tid = threadIdx.x;
  int wave = tid >> 6, lane = tid & 63;
  int i = blockIdx.x*4 + wave;
  const unsigned short* row = M + ((long)b*NTOK + i)*NTOK;
  const float* xb = x + b*NTOK;
  float s0 = 0.f, s1 = 0.f;
  #pragma unroll
  for (int k=0;k<4;k++){
    int j = k*512 + lane*8;
    f16x8 mv = *(const f16x8*)(row + j);
    float4 x0 = *(const float4*)(xb + j);
    float4 x1 = *(const float4*)(xb + j + 4);
    s0 += (float)mv[0]*x0.x + (float)mv[2]*x0.z + (float)mv[4]*x1.x + (float)mv[6]*x1.z;
    s1 += (float)mv[1]*x0.y + (float)mv[3]*x0.w + (float)mv[5]*x1.y + (float)mv[7]*x1.w;
  }
  float s = wred_sumf(s0 + s1);
  if (lane == 0){
    float yi = y[b*NTOK + i];
    y[b*NTOK + i] = yi / (yi*s + EPSF);
  }
}

// argmax over P[i,:]*v using the f16 avgH (quantization << bf16 QK^T noise)
__global__ __launch_bounds__(256) void argmax_kernel(const unsigned short* __restrict__ P,
    const float* __restrict__ v, const int* __restrict__ perm,
    float* __restrict__ dout_perm)
{
  int b = blockIdx.y, tid = threadIdx.x;
  int wave = tid >> 6, lane = tid & 63;
  int i = blockIdx.x*4 + wave;
  const unsigned short* row = P + ((long)b*NTOK + i)*NTOK;
  const float* vb = v + b*NTOK;
  float bv = -1.0f; int bj = 0;
  #pragma unroll
  for (int k=0;k<4;k++){
    int j0 = k*512 + lane*8;
    f16x8 mv = *(const f16x8*)(row + j0);
    #pragma unroll
    for (int e=0;e<8;e++){
      float val = (float)mv[e]*vb[j0+e];
      if (val>bv){ bv=val; bj=j0+e; }
    }
  }
  for (int o=32;o;o>>=1){
    float ov=__shfl_xor(bv,o); int oj=__shfl_xor(bj,o);
    if (ov>bv || (ov==bv && oj<bj)){bv=ov;bj=oj;}
  }
  if (lane == 0)
    dout_perm[b*NTOK + i] = (float)perm[b*NTOK + bj];
}

__global__ __launch_bounds__(256) void out_kernel(
    const unsigned short* __restrict__ Ob, const unsigned short* __restrict__ Wob,
    const float* __restrict__ bo, float* __restrict__ dout)
{
  __shared__ unsigned short lds[(128+128)*32];
  int m0 = blockIdx.x*128, n0 = blockIdx.y*128;
  f32x4 acc[4][4];
  f32x4 z = {0.f,0.f,0.f,0.f};
  for (int i=0;i<4;i++) for(int j=0;j<4;j++) acc[i][j] = z;
  gemm_bt_core<128,128>(Ob + (long)m0*DMODEL, DMODEL, Wob + (long)n0*DMODEL, DMODEL,
                        DMODEL, acc, lds, lds + 128*32);
  int lane = threadIdx.x & 63, wave = threadIdx.x >> 6;
  int wm = wave>>1, wn = wave&1;
  int cr = (lane>>4)<<2, cc = lane & 15;
  for (int i=0;i<4;i++) for(int j=0;j<4;j++) for(int r=0;r<4;r++){
    int row = m0 + wm*64 + i*16 + cr + r;
    int col = n0 + wn*64 + j*16 + cc;
    dout[(long)row*DMODEL + col] = acc[i][j][r] + bo[col];
  }
}

__global__ void cert_kernel(const float* __restrict__ cert,
    const float* __restrict__ ctemp, const float* __restrict__ entb,
    float* __restrict__ dout_cert)
{
  int idx = blockIdx.x*256+threadIdx.x;
  if (idx >= BATCH*NTOK) return;
  int b = idx >> 11, row = idx & 2047;
  float s = 0.f;
  #pragma unroll
  for (int h=0; h<NHEADS; h++) s += entb[((long)(b*NHEADS+h))*NTOK + row];
  float ent = -s * (1.0f/16.0f);
  float ct = ctemp[0];
  float arg = ct * (logf((float)NTOK) - ent);
  float upd = 1.0f/(1.0f+expf(-arg));
  dout_cert[idx] = fmaxf(cert[idx], upd);
}

extern "C" void kernel_launch(void* const* d_in, const int* in_sizes, int n_in,
                              void* d_out, int out_size, void* d_ws, size_t ws_size,
                              hipStream_t stream)
{
  const float* x    = (const float*)d_in[0];
  const float* cert = (const float*)d_in[1];
  const int*   perm = (const int*)d_in[2];
  const float* Wq   = (const float*)d_in[3];
  const float* bq   = (const float*)d_in[4];
  const float* Wk   = (const float*)d_in[5];
  const float* bk   = (const float*)d_in[6];
  const float* Wv   = (const float*)d_in[7];
  const float* bv   = (const float*)d_in[8];
  const float* Wo   = (const float*)d_in[9];
  const float* bo   = (const float*)d_in[10];
  const float* psc  = (const float*)d_in[11];
  const float* ctmp = (const float*)d_in[12];
  float* dout = (float*)d_out;

  // layout: f32 u/v, f32 arrays, split-K partials, bf16/f16 region
  float* u     = (float*)d_ws;                          // 4096
  float* v     = u + 4096;                              // 4096
  float* avg   = v + 4096;                              // 8,388,608 f32 (unused, kept for layout)
  float* mbuf  = avg   + 8388608;                       // 65,536
  float* ilbuf = mbuf  + 65536;                         // 65,536
  float* entb  = ilbuf + 65536;                         // 65,536
  float* mpart = entb  + 65536;                         // 131,072 (2 halves)
  float* lpart = mpart + 131072;                        // 131,072
  float* Tpart = lpart + 131072;                        // 131,072
  unsigned short* Opart = (unsigned short*)(Tpart + 131072);  // 8,388,608 bf16
  unsigned short* xb  = Opart + 8388608;                // 4,194,304
  unsigned short* Wqb = xb  + 4194304;
  unsigned short* Wkb = Wqb + 1048576;
  unsigned short* Wvb = Wkb + 1048576;
  unsigned short* Wob = Wvb + 1048576;
  unsigned short* Qb  = Wob + 1048576;                  // 4,194,304 each
  unsigned short* Kb  = Qb  + 4194304;
  unsigned short* Vb  = Kb  + 4194304;
  unsigned short* Vt  = Vb  + 4194304;                  // f16 after vtrans
  unsigned short* Ob  = Vt  + 4194304;                  // 4,194,304
  // overlays (regions dead by the time these are written):
  unsigned short* avgH = Opart;                         // f16 row-major (Opart dead after merge)
  unsigned short* avgT = Vb;                            // f16 transposed (Vb+Vt dead after attnA)

  f2b_multi<<<dim3(8192),256,0,stream>>>(x, Wq, Wk, Wv, Wo, xb, u);

  qkv_kernel<<<dim3(32,24),256,0,stream>>>(xb, Wqb,bq, Wkb,bk, Wvb,bv, Qb,Kb,Vb);
  vtrans_kernel<<<dim3(64,32,2), dim3(32,8),0,stream>>>(Vb, Vt);

  attnA_kernel<<<dim3(32,NHEADS,2),512,0,stream>>>(Qb, Kb, Vt, perm, psc,
      mpart, lpart, Tpart, Opart);
  merge_kernel<<<dim3(512,2),256,0,stream>>>(mpart, lpart, Tpart, Opart,
      Ob, mbuf, ilbuf, entb);
  avgP_kernel<<<dim3(1024),512,0,stream>>>(Qb, Kb, perm, psc, mbuf, ilbuf,
      avgH, avgT);

  for (int it=0; it<10; it++){
    sink_phase_h<<<dim3(512,2),256,0,stream>>>(avgH, v, u);
    sink_phase_h<<<dim3(512,2),256,0,stream>>>(avgT, u, v);
  }
  argmax_kernel<<<dim3(512,2),256,0,stream>>>(avgH, v, perm, dout + 4194304 + 4096);

  out_kernel <<<dim3(32,8),256,0,stream>>>(Ob, Wob, bo, dout);
  cert_kernel<<<dim3(16), 256,0,stream>>>(cert, ctmp, entb, dout + 4194304);
}